// Round 12
// baseline (244.969 us; speedup 1.0000x reference)
//
#include <hip/hip_runtime.h>
#include <hip/hip_bf16.h>

typedef __attribute__((ext_vector_type(8))) short short8;
typedef __attribute__((ext_vector_type(4))) short short4x;
typedef __attribute__((ext_vector_type(4))) float floatx4;
typedef __attribute__((ext_vector_type(16))) float floatx16;
typedef __attribute__((ext_vector_type(4))) unsigned uintx4;

__device__ __forceinline__ short f2bf(float f) {
    unsigned u = __float_as_uint(f);
    u = u + 0x7fffu + ((u >> 16) & 1u);
    return (short)(u >> 16);
}
// truncating convert (values >=0, used for P only)
__device__ __forceinline__ short f2bf_rz(float f) {
    return (short)(__float_as_uint(f) >> 16);
}

static constexpr int B_ = 4, S_ = 2048, D_ = 1024, H_ = 16, DH_ = 64;
// Q pre-scale: 1/sqrt(DH) * log2(e), so attention scores are in log2 domain
static constexpr float QSCALE = 0.125f * 1.4426950408889634f;

// ---------------------------------------------------------------------------
// x convert: f32 -> bf16, 8 elements/thread
// ---------------------------------------------------------------------------
__global__ __launch_bounds__(256) void convert_x(const float* __restrict__ in,
                                                 short* __restrict__ out, int n8) {
    int i = blockIdx.x * 256 + threadIdx.x;
    if (i >= n8) return;
    const float4* p = (const float4*)(in + (size_t)i * 8);
    float4 a = p[0], b = p[1];
    short8 v;
    v[0] = f2bf(a.x); v[1] = f2bf(a.y); v[2] = f2bf(a.z); v[3] = f2bf(a.w);
    v[4] = f2bf(b.x); v[5] = f2bf(b.y); v[6] = f2bf(b.z); v[7] = f2bf(b.w);
    *(short8*)(out + (size_t)i * 8) = v;
}

// ---------------------------------------------------------------------------
// Merged weight prep: transpose + f32->bf16 for Wq/Wk/Wv (z=0..2, y=head) and
// Wo (z=3, y=n-tile). grid (16, 16, 4).
// ---------------------------------------------------------------------------
__global__ __launch_bounds__(256) void prep_weights(const float* __restrict__ Wq,
                                                    const float* __restrict__ Wk,
                                                    const float* __restrict__ Wv,
                                                    const float* __restrict__ Wo,
                                                    short* __restrict__ WqT,
                                                    short* __restrict__ WkT,
                                                    short* __restrict__ WvT,
                                                    short* __restrict__ WoT) {
    __shared__ alignas(16) float t[64 * 68];
    int z = blockIdx.z;
    const float* in;
    short* out;
    int N, M = D_, n0;
    if (z < 3) {
        const float* I = (z == 0) ? Wq : (z == 1) ? Wk : Wv;
        short* O = (z == 0) ? WqT : (z == 1) ? WkT : WvT;
        in = I + (size_t)blockIdx.y * D_ * DH_;
        out = O + (size_t)blockIdx.y * D_ * DH_;
        N = DH_; n0 = 0;
    } else {
        in = Wo; out = WoT; N = D_; n0 = blockIdx.y * 64;
    }
    int m0 = blockIdx.x * 64;
    int tid = threadIdx.x;
#pragma unroll
    for (int i = 0; i < 4; ++i) {
        int c = tid + i * 256;
        int row = c >> 4, c4 = (c & 15) * 4;
        float4 v = *(const float4*)(in + (size_t)(m0 + row) * N + n0 + c4);
        *(float4*)(t + row * 68 + c4) = v;
    }
    __syncthreads();
#pragma unroll
    for (int i = 0; i < 2; ++i) {
        int c = tid + i * 256;
        int row = c >> 3, c8 = (c & 7) * 8;
        short8 v;
#pragma unroll
        for (int j = 0; j < 8; ++j) v[j] = f2bf(t[(c8 + j) * 68 + row]);
        *(short8*)(out + (size_t)(n0 + row) * M + m0 + c8) = v;
    }
}

// ---------------------------------------------------------------------------
// m97-style 128x128 GEMM core with XOR-swizzled LDS chunks (validated r6:
// conflicts 1.9e7 -> 2e5).
// ---------------------------------------------------------------------------
__device__ __forceinline__ void gemm128_core(const short* __restrict__ A,
                                             const short* __restrict__ Bm,
                                             short* ldsA, short* ldsB,
                                             int m0, int n0,
                                             floatx4 (&acc)[4][4],
                                             int w, int lane, int quad, int lm) {
    const int K = 1024;
    int wm = (w >> 1) * 64, wn = (w & 1) * 64;
    int rsub = lane >> 3;                       // row-within-8-group
    int csw = ((lane & 7) ^ rsub) * 8;          // swizzled global k-chunk offset (shorts)
    int lmx = lm & 7;                           // reader swizzle key
    for (int k0 = 0; k0 < K; k0 += 64) {
#pragma unroll
        for (int i = 0; i < 4; ++i) {
            int r0 = w * 32 + i * 8;
            const short* ga = A + (size_t)(m0 + r0 + rsub) * K + k0 + csw;
            __builtin_amdgcn_global_load_lds((const __attribute__((address_space(1))) void*)ga,
                                             (__attribute__((address_space(3))) void*)(ldsA + r0 * 64),
                                             16, 0, 0);
            const short* gb = Bm + (size_t)(n0 + r0 + rsub) * K + k0 + csw;
            __builtin_amdgcn_global_load_lds((const __attribute__((address_space(1))) void*)gb,
                                             (__attribute__((address_space(3))) void*)(ldsB + r0 * 64),
                                             16, 0, 0);
        }
        __syncthreads();
#pragma unroll
        for (int ks = 0; ks < 2; ++ks) {
            short8 am[4], bn[4];
#pragma unroll
            for (int i = 0; i < 4; ++i)
                am[i] = *(const short8*)(ldsA + (wm + i * 16 + lm) * 64 + (((ks * 4 + quad) ^ lmx) << 3));
#pragma unroll
            for (int i = 0; i < 4; ++i)
                bn[i] = *(const short8*)(ldsB + (wn + i * 16 + lm) * 64 + (((ks * 4 + quad) ^ lmx) << 3));
#pragma unroll
            for (int mi = 0; mi < 4; ++mi)
#pragma unroll
                for (int ni = 0; ni < 4; ++ni)
                    acc[mi][ni] = __builtin_amdgcn_mfma_f32_16x16x32_bf16(am[mi], bn[ni], acc[mi][ni], 0, 0, 0);
        }
        __syncthreads();
    }
}

// ---------------------------------------------------------------------------
// QKV projection: 1D grid 1536 with bijective XCD swizzle (r11).
// Decode: xcd = bid&7, j = bid>>3; x = xcd*8 + (j&7); y = (j>>3)&7; z = j>>6.
// XCD k owns m0-range [k*1024, k*1024+1024) (8 A panels, 2 MB): its ~96
// concurrent blocks cycle x%8 fastest -> A panels stay L2-hot and are fetched
// ONCE per XCD; B panels (256 KB, L3-resident) stream one per (y,z) group.
// A = xb [8192][1024]. B = W?T [1024 n][1024 k].
// z=0 -> Q[b,h,s,e] pre-scaled by QSCALE; z=1 -> K[b,h,s,e]; z=2 -> VT[(b*1024+n)][s]
// ---------------------------------------------------------------------------
__global__ __launch_bounds__(256, 3) void qkv_gemm128(const short* __restrict__ xb,
                                                      const short* __restrict__ WqT,
                                                      const short* __restrict__ WkT,
                                                      const short* __restrict__ WvT,
                                                      short* __restrict__ Q,
                                                      short* __restrict__ K,
                                                      short* __restrict__ VT) {
    __shared__ alignas(16) short lds[16384];  // 32 KB: staging A|B, reused as epilogue bounce
    short* ldsA = lds;
    short* ldsB = lds + 8192;
    int bid = blockIdx.x;
    int xcd = bid & 7, j = bid >> 3;
    int xg = xcd * 8 + (j & 7);
    int yz = j >> 3;                 // [0, 24)
    int yg = yz & 7, z = yz >> 3;
    int m0 = xg * 128, n0 = yg * 128;
    const short* Bm = (z == 0) ? WqT : (z == 1) ? WkT : WvT;
    int tid = threadIdx.x, w = tid >> 6, lane = tid & 63, quad = lane >> 4, lm = lane & 15;

    floatx4 acc[4][4];
#pragma unroll
    for (int mi = 0; mi < 4; ++mi)
#pragma unroll
        for (int ni = 0; ni < 4; ++ni) acc[mi][ni] = (floatx4)0.0f;

    gemm128_core(xb, Bm, ldsA, ldsB, m0, n0, acc, w, lane, quad, lm);

    int wm = (w >> 1) * 64, wn = (w & 1) * 64;
    int b = m0 >> 11;
    int sbase = m0 & 2047;

    if (z < 2) {
        short* O = (z == 0) ? Q : K;
        float scale = (z == 0) ? QSCALE : 1.0f;
        short* t = lds;  // 128 x 68
#pragma unroll
        for (int ph = 0; ph < 2; ++ph) {
            if (ph) __syncthreads();
            if ((w & 1) == ph) {
#pragma unroll
                for (int mi = 0; mi < 4; ++mi)
#pragma unroll
                    for (int ni = 0; ni < 4; ++ni)
#pragma unroll
                        for (int r = 0; r < 4; ++r)
                            t[(wm + mi * 16 + quad * 4 + r) * 68 + ni * 16 + lm] =
                                f2bf(acc[mi][ni][r] * scale);
            }
            __syncthreads();
            int h = (n0 + ph * 64) >> 6;
            size_t obase = ((size_t)(b * 16 + h) * 2048 + sbase) * 64;
#pragma unroll
            for (int i = 0; i < 4; ++i) {
                int c = tid + i * 256;
                int m = c >> 3, e8 = (c & 7) * 8;
                short8 v = *(const short8*)(t + m * 68 + e8);
                *(short8*)(O + obase + (size_t)m * 64 + e8) = v;
            }
        }
    } else {
        // transpose 128x128 tile through LDS (two 64-n halves) -> VT[b*1024+n][s]
        short* t = lds;  // 64 x 136
#pragma unroll
        for (int ph = 0; ph < 2; ++ph) {
            if (ph) __syncthreads();
            if ((w & 1) == ph) {
#pragma unroll
                for (int mi = 0; mi < 4; ++mi)
#pragma unroll
                    for (int ni = 0; ni < 4; ++ni) {
                        int nl = ni * 16 + lm;
#pragma unroll
                        for (int r = 0; r < 4; ++r) {
                            int ml = wm + mi * 16 + quad * 4 + r;
                            t[nl * 136 + ml] = f2bf(acc[mi][ni][r]);
                        }
                    }
            }
            __syncthreads();
#pragma unroll
            for (int i = 0; i < 4; ++i) {
                int c = tid + i * 256;
                int rowl = c >> 4, colc = (c & 15) * 8;
                short8 v = *(const short8*)(t + rowl * 136 + colc);
                size_t n = n0 + ph * 64 + rowl;
                *(short8*)(VT + ((size_t)b * 1024 + n) * 2048 + sbase + colc) = v;
            }
        }
    }
}

// ---------------------------------------------------------------------------
// Output projection: out[8192][1024] f32 = CC @ WoT^T + bo. 1D grid 512 with
// the same bijective XCD swizzle (xcd = bid&7 owns 8 contiguous CC panels).
// ---------------------------------------------------------------------------
__global__ __launch_bounds__(256, 3) void outproj128(const short* __restrict__ CC,
                                                     const short* __restrict__ WoT,
                                                     const float* __restrict__ bo,
                                                     float* __restrict__ out) {
    __shared__ alignas(16) short lds[16384];
    short* ldsA = lds;
    short* ldsB = lds + 8192;
    int bid = blockIdx.x;
    int xcd = bid & 7, j = bid >> 3;
    int xg = xcd * 8 + (j & 7);
    int yg = j >> 3;                 // [0, 8)
    int m0 = xg * 128, n0 = yg * 128;
    int tid = threadIdx.x, w = tid >> 6, lane = tid & 63, quad = lane >> 4, lm = lane & 15;

    floatx4 acc[4][4];
#pragma unroll
    for (int mi = 0; mi < 4; ++mi)
#pragma unroll
        for (int ni = 0; ni < 4; ++ni) acc[mi][ni] = (floatx4)0.0f;

    gemm128_core(CC, WoT, ldsA, ldsB, m0, n0, acc, w, lane, quad, lm);

    int wm = (w >> 1) * 64, wn = (w & 1) * 64;
#pragma unroll
    for (int mi = 0; mi < 4; ++mi)
#pragma unroll
        for (int ni = 0; ni < 4; ++ni) {
            int n = n0 + wn + ni * 16 + lm;
            float bb = bo[n];
#pragma unroll
            for (int r = 0; r < 4; ++r) {
                int m = m0 + wm + mi * 16 + quad * 4 + r;
                out[(size_t)m * 1024 + n] = acc[mi][ni][r] + bb;
            }
        }
}

// ---------------------------------------------------------------------------
// Causal flash attention v11 (r9 version, REVERTED from r11's grid split):
// 32x32 MFMA, in-register P via cvt_pk+permlane32_swap (T12), single-buffered
// K/V staging, ps-paired grid (64 bh, 8 pi) — 71.9 us measured, best attn.
// r10: explicit dbuf neutral (matches m99/m100). r11: 1-tile-per-block grid
// split neutral on clean timing, worse under profiling. Both reverted.
// bh fastest-varying pins each bh's K/V to one XCD L2 (FETCH 146 -> 30 MB).
// LDS: Kt 16K + Vt 16K = 32 KB.
// ---------------------------------------------------------------------------
__global__ __launch_bounds__(256, 2) void attn_kernel(const short* __restrict__ Q,
                                                      const short* __restrict__ Kb,
                                                      const short* __restrict__ VT,
                                                      short* __restrict__ CC) {
    __shared__ alignas(16) short Kt[128 * 64];   // swizzled chunks
    __shared__ alignas(16) short Vt[64 * 128];   // swizzled chunks
    int bh = blockIdx.x;
    int pi = blockIdx.y;
    int b = bh >> 4, h = bh & 15;
    int tid = threadIdx.x;
    int w = tid >> 6, l = tid & 63;
    int hi = l >> 5, l31 = l & 31, l7 = l & 7;
    int rsub = l >> 3;              // K staging row-within-8
    int csw = ((l & 7) ^ rsub) * 8; // K staging swizzled chunk offset
    int vr4 = l >> 4;               // V staging row-within-4
    int vc = l & 15;

    const short* Qbh = Q + (size_t)bh * S_ * DH_;
    const short* Kbh = Kb + (size_t)bh * S_ * DH_;
    const short* Vbh = VT + (size_t)bh * 64 * S_;

    for (int ps = 0; ps < 2; ++ps) {
        int qt = ps ? (15 - pi) : pi;
        int q0 = qt * 128;
        int qrow = q0 + w * 32 + l31;   // the q-row this lane's S^T column owns

        // Q B-frags: col q = lane&31, k = ks*16 + hi*8 + j
        short8 qa[4];
        const short* Qrow = Qbh + (size_t)qrow * DH_;
#pragma unroll
        for (int ks = 0; ks < 4; ++ks)
            qa[ks] = *(const short8*)(Qrow + ks * 16 + hi * 8);

        floatx16 acc[2];
        acc[0] = (floatx16)0.0f;
        acc[1] = (floatx16)0.0f;
        float lsum = 0.0f;

        int nkt = qt + 1;
        for (int kt = 0; kt < nkt; ++kt) {
            int t0 = kt * 128;
            // stage Kt[128][64] (rows contiguous) and Vt[64][128] (rows stride S_)
            const short* Ktile = Kbh + (size_t)t0 * DH_;
#pragma unroll
            for (int i = 0; i < 4; ++i) {
                int r0 = w * 32 + i * 8;
                const short* ga = Ktile + (size_t)(r0 + rsub) * 64 + csw;
                __builtin_amdgcn_global_load_lds((const __attribute__((address_space(1))) void*)ga,
                                                 (__attribute__((address_space(3))) void*)(Kt + r0 * 64),
                                                 16, 0, 0);
            }
#pragma unroll
            for (int i = 0; i < 4; ++i) {
                int r0v = w * 16 + i * 4;
                int row = r0v + vr4;
                const short* gv = Vbh + (size_t)row * S_ + t0 + ((vc ^ (row & 7)) * 8);
                __builtin_amdgcn_global_load_lds((const __attribute__((address_space(1))) void*)gv,
                                                 (__attribute__((address_space(3))) void*)(Vt + r0v * 128),
                                                 16, 0, 0);
            }
            __syncthreads();

            // QK^T: S^T[t=128][q=128] ; wave covers its 32 q for all 128 t
            floatx16 st[4];
            __builtin_amdgcn_s_setprio(1);
#pragma unroll
            for (int tb = 0; tb < 4; ++tb) {
                floatx16 t = (floatx16)0.0f;
#pragma unroll
                for (int ks = 0; ks < 4; ++ks) {
                    // A=K frag: row t = tb*32 + lane&31, k = ks*16 + hi*8 + j
                    short8 kf = *(const short8*)(Kt + (tb * 32 + l31) * 64 +
                                                 (((ks * 2 + hi) ^ l7) << 3));
                    t = __builtin_amdgcn_mfma_f32_32x32x16_bf16(kf, qa[ks], t, 0, 0, 0);
                }
                st[tb] = t;
            }
            __builtin_amdgcn_s_setprio(0);

            if (kt == nkt - 1) {
#pragma unroll
                for (int tb = 0; tb < 4; ++tb)
#pragma unroll
                    for (int r = 0; r < 16; ++r) {
                        int t_ = t0 + tb * 32 + (r & 3) + 8 * (r >> 2) + 4 * hi;
                        if (t_ > qrow) st[tb][r] = -INFINITY;
                    }
            }

            // exp2 (scores pre-scaled into log2 domain) + row-sum (lane owns q)
#pragma unroll
            for (int tb = 0; tb < 4; ++tb)
#pragma unroll
                for (int r = 0; r < 16; r += 4) {
                    float p0 = exp2f(st[tb][r]);
                    float p1 = exp2f(st[tb][r + 1]);
                    float p2 = exp2f(st[tb][r + 2]);
                    float p3 = exp2f(st[tb][r + 3]);
                    st[tb][r] = p0; st[tb][r + 1] = p1;
                    st[tb][r + 2] = p2; st[tb][r + 3] = p3;
                    lsum += (p0 + p1) + (p2 + p3);
                }

            // PV: build P A-frags in registers (cvt_pk + permlane32_swap), no LDS
            __builtin_amdgcn_s_setprio(1);
#pragma unroll
            for (int tb = 0; tb < 4; ++tb)
#pragma unroll
                for (int sl = 0; sl < 2; ++sl) {
                    unsigned x0, y0, x1, y1;
                    asm("v_cvt_pk_bf16_f32 %0, %1, %2" : "=v"(x0)
                        : "v"(st[tb][sl * 8 + 0]), "v"(st[tb][sl * 8 + 1]));
                    asm("v_cvt_pk_bf16_f32 %0, %1, %2" : "=v"(y0)
                        : "v"(st[tb][sl * 8 + 4]), "v"(st[tb][sl * 8 + 5]));
                    asm("v_cvt_pk_bf16_f32 %0, %1, %2" : "=v"(x1)
                        : "v"(st[tb][sl * 8 + 2]), "v"(st[tb][sl * 8 + 3]));
                    asm("v_cvt_pk_bf16_f32 %0, %1, %2" : "=v"(y1)
                        : "v"(st[tb][sl * 8 + 6]), "v"(st[tb][sl * 8 + 7]));
                    // x' = [x_lo, y_lo] -> dword0/1 ; y' = [x_hi, y_hi] -> dword2/3
                    asm("v_permlane32_swap_b32 %0, %1" : "+v"(x0), "+v"(y0));
                    asm("v_permlane32_swap_b32 %0, %1" : "+v"(x1), "+v"(y1));
                    uintx4 pd;
                    pd[0] = x0; pd[1] = x1; pd[2] = y0; pd[3] = y1;
                    short8 pa = __builtin_bit_cast(short8, pd);
                    int s = tb * 2 + sl;
#pragma unroll
                    for (int eb = 0; eb < 2; ++eb) {
                        // B=V frag: col e = eb*32 + lane&31, k = t = s*16 + hi*8 + j
                        short8 v = *(const short8*)(Vt + (eb * 32 + l31) * 128 +
                                                    (((s * 2 + hi) ^ l7) << 3));
                        acc[eb] = __builtin_amdgcn_mfma_f32_32x32x16_bf16(pa, v, acc[eb], 0, 0, 0);
                    }
                }
            __builtin_amdgcn_s_setprio(0);
            __syncthreads();  // protects Kt/Vt restage next iteration
        }

        // each q's full row-sum lives split across lane and lane^32
        float lt = lsum + __shfl_xor(lsum, 32);
        float invl = 1.0f / lt;

        // O layout: row q_local = (r&3)+8*(r>>2)+4*hi, col e = eb*32 + lane&31
#pragma unroll
        for (int r = 0; r < 16; ++r) {
            int q_local = (r & 3) + 8 * (r >> 2) + 4 * hi;
            float iv = __shfl(invl, q_local);  // invl for q=q_local lives at lane q_local
            int row = q0 + w * 32 + q_local;
            short* OC = CC + ((size_t)b * S_ + row) * D_ + h * DH_;
#pragma unroll
            for (int eb = 0; eb < 2; ++eb)
                OC[eb * 32 + l31] = f2bf(acc[eb][r] * iv);
        }
    }
}

extern "C" void kernel_launch(void* const* d_in, const int* in_sizes, int n_in,
                              void* d_out, int out_size, void* d_ws, size_t ws_size,
                              hipStream_t stream) {
    const float* x  = (const float*)d_in[0];
    const float* Wq = (const float*)d_in[1];
    const float* Wk = (const float*)d_in[2];
    const float* Wv = (const float*)d_in[3];
    const float* Wo = (const float*)d_in[4];
    const float* bo = (const float*)d_in[5];
    float* out = (float*)d_out;
    short* ws = (short*)d_ws;

    const size_t WSZ = (size_t)H_ * D_ * DH_;        // 1,048,576
    const size_t QSZ = (size_t)B_ * H_ * S_ * DH_;   // 8,388,608
    short* WqT = ws;
    short* WkT = WqT + WSZ;
    short* WvT = WkT + WSZ;
    short* WoT = WvT + WSZ;
    short* xb  = WoT + (size_t)D_ * D_;
    short* Qb  = xb + (size_t)B_ * S_ * D_;
    short* Kb  = Qb + QSZ;
    short* VTb = Kb + QSZ;
    short* CCb = VTb + QSZ;

    convert_x<<<(B_ * S_ * D_ / 8 + 255) / 256, 256, 0, stream>>>(x, xb, B_ * S_ * D_ / 8);
    prep_weights<<<dim3(16, 16, 4), 256, 0, stream>>>(Wq, Wk, Wv, Wo, WqT, WkT, WvT, WoT);
    qkv_gemm128<<<1536, 256, 0, stream>>>(xb, WqT, WkT, WvT, Qb, Kb, VTb);
    attn_kernel<<<dim3(64, 8), 256, 0, stream>>>(Qb, Kb, VTb, CCb);
    outproj128<<<512, 256, 0, stream>>>(CCb, WoT, bo, out);
}

// Round 13
// 232.860 us; speedup vs baseline: 1.0520x; 1.0520x over previous
//
#include <hip/hip_runtime.h>
#include <hip/hip_bf16.h>

typedef __attribute__((ext_vector_type(8))) short short8;
typedef __attribute__((ext_vector_type(4))) short short4x;
typedef __attribute__((ext_vector_type(4))) float floatx4;
typedef __attribute__((ext_vector_type(16))) float floatx16;
typedef __attribute__((ext_vector_type(4))) unsigned uintx4;

__device__ __forceinline__ short f2bf(float f) {
    unsigned u = __float_as_uint(f);
    u = u + 0x7fffu + ((u >> 16) & 1u);
    return (short)(u >> 16);
}
// truncating convert (values >=0, used for P only)
__device__ __forceinline__ short f2bf_rz(float f) {
    return (short)(__float_as_uint(f) >> 16);
}

static constexpr int B_ = 4, S_ = 2048, D_ = 1024, H_ = 16, DH_ = 64;
// Q pre-scale: 1/sqrt(DH) * log2(e), so attention scores are in log2 domain
static constexpr float QSCALE = 0.125f * 1.4426950408889634f;

// ---------------------------------------------------------------------------
// x convert: f32 -> bf16, 8 elements/thread
// ---------------------------------------------------------------------------
__global__ __launch_bounds__(256) void convert_x(const float* __restrict__ in,
                                                 short* __restrict__ out, int n8) {
    int i = blockIdx.x * 256 + threadIdx.x;
    if (i >= n8) return;
    const float4* p = (const float4*)(in + (size_t)i * 8);
    float4 a = p[0], b = p[1];
    short8 v;
    v[0] = f2bf(a.x); v[1] = f2bf(a.y); v[2] = f2bf(a.z); v[3] = f2bf(a.w);
    v[4] = f2bf(b.x); v[5] = f2bf(b.y); v[6] = f2bf(b.z); v[7] = f2bf(b.w);
    *(short8*)(out + (size_t)i * 8) = v;
}

// ---------------------------------------------------------------------------
// Merged weight prep: transpose + f32->bf16 for Wq/Wk/Wv (z=0..2, y=head) and
// Wo (z=3, y=n-tile). grid (16, 16, 4).
// ---------------------------------------------------------------------------
__global__ __launch_bounds__(256) void prep_weights(const float* __restrict__ Wq,
                                                    const float* __restrict__ Wk,
                                                    const float* __restrict__ Wv,
                                                    const float* __restrict__ Wo,
                                                    short* __restrict__ WqT,
                                                    short* __restrict__ WkT,
                                                    short* __restrict__ WvT,
                                                    short* __restrict__ WoT) {
    __shared__ alignas(16) float t[64 * 68];
    int z = blockIdx.z;
    const float* in;
    short* out;
    int N, M = D_, n0;
    if (z < 3) {
        const float* I = (z == 0) ? Wq : (z == 1) ? Wk : Wv;
        short* O = (z == 0) ? WqT : (z == 1) ? WkT : WvT;
        in = I + (size_t)blockIdx.y * D_ * DH_;
        out = O + (size_t)blockIdx.y * D_ * DH_;
        N = DH_; n0 = 0;
    } else {
        in = Wo; out = WoT; N = D_; n0 = blockIdx.y * 64;
    }
    int m0 = blockIdx.x * 64;
    int tid = threadIdx.x;
#pragma unroll
    for (int i = 0; i < 4; ++i) {
        int c = tid + i * 256;
        int row = c >> 4, c4 = (c & 15) * 4;
        float4 v = *(const float4*)(in + (size_t)(m0 + row) * N + n0 + c4);
        *(float4*)(t + row * 68 + c4) = v;
    }
    __syncthreads();
#pragma unroll
    for (int i = 0; i < 2; ++i) {
        int c = tid + i * 256;
        int row = c >> 3, c8 = (c & 7) * 8;
        short8 v;
#pragma unroll
        for (int j = 0; j < 8; ++j) v[j] = f2bf(t[(c8 + j) * 68 + row]);
        *(short8*)(out + (size_t)(n0 + row) * M + m0 + c8) = v;
    }
}

// ---------------------------------------------------------------------------
// m97-style 128x128 GEMM core with XOR-swizzled LDS chunks (validated r6:
// conflicts 1.9e7 -> 2e5).
// ---------------------------------------------------------------------------
__device__ __forceinline__ void gemm128_core(const short* __restrict__ A,
                                             const short* __restrict__ Bm,
                                             short* ldsA, short* ldsB,
                                             int m0, int n0,
                                             floatx4 (&acc)[4][4],
                                             int w, int lane, int quad, int lm) {
    const int K = 1024;
    int wm = (w >> 1) * 64, wn = (w & 1) * 64;
    int rsub = lane >> 3;                       // row-within-8-group
    int csw = ((lane & 7) ^ rsub) * 8;          // swizzled global k-chunk offset (shorts)
    int lmx = lm & 7;                           // reader swizzle key
    for (int k0 = 0; k0 < K; k0 += 64) {
#pragma unroll
        for (int i = 0; i < 4; ++i) {
            int r0 = w * 32 + i * 8;
            const short* ga = A + (size_t)(m0 + r0 + rsub) * K + k0 + csw;
            __builtin_amdgcn_global_load_lds((const __attribute__((address_space(1))) void*)ga,
                                             (__attribute__((address_space(3))) void*)(ldsA + r0 * 64),
                                             16, 0, 0);
            const short* gb = Bm + (size_t)(n0 + r0 + rsub) * K + k0 + csw;
            __builtin_amdgcn_global_load_lds((const __attribute__((address_space(1))) void*)gb,
                                             (__attribute__((address_space(3))) void*)(ldsB + r0 * 64),
                                             16, 0, 0);
        }
        __syncthreads();
#pragma unroll
        for (int ks = 0; ks < 2; ++ks) {
            short8 am[4], bn[4];
#pragma unroll
            for (int i = 0; i < 4; ++i)
                am[i] = *(const short8*)(ldsA + (wm + i * 16 + lm) * 64 + (((ks * 4 + quad) ^ lmx) << 3));
#pragma unroll
            for (int i = 0; i < 4; ++i)
                bn[i] = *(const short8*)(ldsB + (wn + i * 16 + lm) * 64 + (((ks * 4 + quad) ^ lmx) << 3));
#pragma unroll
            for (int mi = 0; mi < 4; ++mi)
#pragma unroll
                for (int ni = 0; ni < 4; ++ni)
                    acc[mi][ni] = __builtin_amdgcn_mfma_f32_16x16x32_bf16(am[mi], bn[ni], acc[mi][ni], 0, 0, 0);
        }
        __syncthreads();
    }
}

// ---------------------------------------------------------------------------
// QKV projection: grid (64, 8, 3). A = xb [8192][1024]. B = W?T [1024 n][1024 k].
// z=0 -> Q[b,h,s,e] pre-scaled by QSCALE; z=1 -> K[b,h,s,e]; z=2 -> VT[(b*1024+n)][s]
// r12: XCD swizzle REVERTED (measured +6.6 us total — concentrating A panels
// per XCD broke the free B-panel L2 reuse of the x-fastest order).
// ---------------------------------------------------------------------------
__global__ __launch_bounds__(256, 3) void qkv_gemm128(const short* __restrict__ xb,
                                                      const short* __restrict__ WqT,
                                                      const short* __restrict__ WkT,
                                                      const short* __restrict__ WvT,
                                                      short* __restrict__ Q,
                                                      short* __restrict__ K,
                                                      short* __restrict__ VT) {
    __shared__ alignas(16) short lds[16384];  // 32 KB: staging A|B, reused as epilogue bounce
    short* ldsA = lds;
    short* ldsB = lds + 8192;
    int m0 = blockIdx.x * 128, n0 = blockIdx.y * 128, z = blockIdx.z;
    const short* Bm = (z == 0) ? WqT : (z == 1) ? WkT : WvT;
    int tid = threadIdx.x, w = tid >> 6, lane = tid & 63, quad = lane >> 4, lm = lane & 15;

    floatx4 acc[4][4];
#pragma unroll
    for (int mi = 0; mi < 4; ++mi)
#pragma unroll
        for (int ni = 0; ni < 4; ++ni) acc[mi][ni] = (floatx4)0.0f;

    gemm128_core(xb, Bm, ldsA, ldsB, m0, n0, acc, w, lane, quad, lm);

    int wm = (w >> 1) * 64, wn = (w & 1) * 64;
    int b = m0 >> 11;
    int sbase = m0 & 2047;

    if (z < 2) {
        short* O = (z == 0) ? Q : K;
        float scale = (z == 0) ? QSCALE : 1.0f;
        short* t = lds;  // 128 x 68
#pragma unroll
        for (int ph = 0; ph < 2; ++ph) {
            if (ph) __syncthreads();
            if ((w & 1) == ph) {
#pragma unroll
                for (int mi = 0; mi < 4; ++mi)
#pragma unroll
                    for (int ni = 0; ni < 4; ++ni)
#pragma unroll
                        for (int r = 0; r < 4; ++r)
                            t[(wm + mi * 16 + quad * 4 + r) * 68 + ni * 16 + lm] =
                                f2bf(acc[mi][ni][r] * scale);
            }
            __syncthreads();
            int h = (n0 + ph * 64) >> 6;
            size_t obase = ((size_t)(b * 16 + h) * 2048 + sbase) * 64;
#pragma unroll
            for (int i = 0; i < 4; ++i) {
                int c = tid + i * 256;
                int m = c >> 3, e8 = (c & 7) * 8;
                short8 v = *(const short8*)(t + m * 68 + e8);
                *(short8*)(O + obase + (size_t)m * 64 + e8) = v;
            }
        }
    } else {
        // transpose 128x128 tile through LDS (two 64-n halves) -> VT[b*1024+n][s]
        short* t = lds;  // 64 x 136
#pragma unroll
        for (int ph = 0; ph < 2; ++ph) {
            if (ph) __syncthreads();
            if ((w & 1) == ph) {
#pragma unroll
                for (int mi = 0; mi < 4; ++mi)
#pragma unroll
                    for (int ni = 0; ni < 4; ++ni) {
                        int nl = ni * 16 + lm;
#pragma unroll
                        for (int r = 0; r < 4; ++r) {
                            int ml = wm + mi * 16 + quad * 4 + r;
                            t[nl * 136 + ml] = f2bf(acc[mi][ni][r]);
                        }
                    }
            }
            __syncthreads();
#pragma unroll
            for (int i = 0; i < 4; ++i) {
                int c = tid + i * 256;
                int rowl = c >> 4, colc = (c & 15) * 8;
                short8 v = *(const short8*)(t + rowl * 136 + colc);
                size_t n = n0 + ph * 64 + rowl;
                *(short8*)(VT + ((size_t)b * 1024 + n) * 2048 + sbase + colc) = v;
            }
        }
    }
}

// ---------------------------------------------------------------------------
// Output projection: out[8192][1024] f32 = CC @ WoT^T + bo. grid (64, 8).
// r12: XCD swizzle reverted (see qkv note).
// ---------------------------------------------------------------------------
__global__ __launch_bounds__(256, 3) void outproj128(const short* __restrict__ CC,
                                                     const short* __restrict__ WoT,
                                                     const float* __restrict__ bo,
                                                     float* __restrict__ out) {
    __shared__ alignas(16) short lds[16384];
    short* ldsA = lds;
    short* ldsB = lds + 8192;
    int m0 = blockIdx.x * 128, n0 = blockIdx.y * 128;
    int tid = threadIdx.x, w = tid >> 6, lane = tid & 63, quad = lane >> 4, lm = lane & 15;

    floatx4 acc[4][4];
#pragma unroll
    for (int mi = 0; mi < 4; ++mi)
#pragma unroll
        for (int ni = 0; ni < 4; ++ni) acc[mi][ni] = (floatx4)0.0f;

    gemm128_core(CC, WoT, ldsA, ldsB, m0, n0, acc, w, lane, quad, lm);

    int wm = (w >> 1) * 64, wn = (w & 1) * 64;
#pragma unroll
    for (int mi = 0; mi < 4; ++mi)
#pragma unroll
        for (int ni = 0; ni < 4; ++ni) {
            int n = n0 + wn + ni * 16 + lm;
            float bb = bo[n];
#pragma unroll
            for (int r = 0; r < 4; ++r) {
                int m = m0 + wm + mi * 16 + quad * 4 + r;
                out[(size_t)m * 1024 + n] = acc[mi][ni][r] + bb;
            }
        }
}

// ---------------------------------------------------------------------------
// Causal flash attention v11 (r9 version — best measured attn, 71.9 us):
// 32x32 MFMA, in-register P via cvt_pk+permlane32_swap (T12), single-buffered
// K/V staging, ps-paired grid (64 bh, 8 pi).
// Tried and reverted: T14 reg-staging (r7, -15%), explicit dbuf (r10,
// neutral, matches m99/m100), 1-tile-per-block grid split (r11, neutral).
// bh fastest-varying pins each bh's K/V to one XCD L2 (FETCH 146 -> 30 MB).
// LDS: Kt 16K + Vt 16K = 32 KB.
// ---------------------------------------------------------------------------
__global__ __launch_bounds__(256, 2) void attn_kernel(const short* __restrict__ Q,
                                                      const short* __restrict__ Kb,
                                                      const short* __restrict__ VT,
                                                      short* __restrict__ CC) {
    __shared__ alignas(16) short Kt[128 * 64];   // swizzled chunks
    __shared__ alignas(16) short Vt[64 * 128];   // swizzled chunks
    int bh = blockIdx.x;
    int pi = blockIdx.y;
    int b = bh >> 4, h = bh & 15;
    int tid = threadIdx.x;
    int w = tid >> 6, l = tid & 63;
    int hi = l >> 5, l31 = l & 31, l7 = l & 7;
    int rsub = l >> 3;              // K staging row-within-8
    int csw = ((l & 7) ^ rsub) * 8; // K staging swizzled chunk offset
    int vr4 = l >> 4;               // V staging row-within-4
    int vc = l & 15;

    const short* Qbh = Q + (size_t)bh * S_ * DH_;
    const short* Kbh = Kb + (size_t)bh * S_ * DH_;
    const short* Vbh = VT + (size_t)bh * 64 * S_;

    for (int ps = 0; ps < 2; ++ps) {
        int qt = ps ? (15 - pi) : pi;
        int q0 = qt * 128;
        int qrow = q0 + w * 32 + l31;   // the q-row this lane's S^T column owns

        // Q B-frags: col q = lane&31, k = ks*16 + hi*8 + j
        short8 qa[4];
        const short* Qrow = Qbh + (size_t)qrow * DH_;
#pragma unroll
        for (int ks = 0; ks < 4; ++ks)
            qa[ks] = *(const short8*)(Qrow + ks * 16 + hi * 8);

        floatx16 acc[2];
        acc[0] = (floatx16)0.0f;
        acc[1] = (floatx16)0.0f;
        float lsum = 0.0f;

        int nkt = qt + 1;
        for (int kt = 0; kt < nkt; ++kt) {
            int t0 = kt * 128;
            // stage Kt[128][64] (rows contiguous) and Vt[64][128] (rows stride S_)
            const short* Ktile = Kbh + (size_t)t0 * DH_;
#pragma unroll
            for (int i = 0; i < 4; ++i) {
                int r0 = w * 32 + i * 8;
                const short* ga = Ktile + (size_t)(r0 + rsub) * 64 + csw;
                __builtin_amdgcn_global_load_lds((const __attribute__((address_space(1))) void*)ga,
                                                 (__attribute__((address_space(3))) void*)(Kt + r0 * 64),
                                                 16, 0, 0);
            }
#pragma unroll
            for (int i = 0; i < 4; ++i) {
                int r0v = w * 16 + i * 4;
                int row = r0v + vr4;
                const short* gv = Vbh + (size_t)row * S_ + t0 + ((vc ^ (row & 7)) * 8);
                __builtin_amdgcn_global_load_lds((const __attribute__((address_space(1))) void*)gv,
                                                 (__attribute__((address_space(3))) void*)(Vt + r0v * 128),
                                                 16, 0, 0);
            }
            __syncthreads();

            // QK^T: S^T[t=128][q=128] ; wave covers its 32 q for all 128 t
            floatx16 st[4];
            __builtin_amdgcn_s_setprio(1);
#pragma unroll
            for (int tb = 0; tb < 4; ++tb) {
                floatx16 t = (floatx16)0.0f;
#pragma unroll
                for (int ks = 0; ks < 4; ++ks) {
                    // A=K frag: row t = tb*32 + lane&31, k = ks*16 + hi*8 + j
                    short8 kf = *(const short8*)(Kt + (tb * 32 + l31) * 64 +
                                                 (((ks * 2 + hi) ^ l7) << 3));
                    t = __builtin_amdgcn_mfma_f32_32x32x16_bf16(kf, qa[ks], t, 0, 0, 0);
                }
                st[tb] = t;
            }
            __builtin_amdgcn_s_setprio(0);

            if (kt == nkt - 1) {
#pragma unroll
                for (int tb = 0; tb < 4; ++tb)
#pragma unroll
                    for (int r = 0; r < 16; ++r) {
                        int t_ = t0 + tb * 32 + (r & 3) + 8 * (r >> 2) + 4 * hi;
                        if (t_ > qrow) st[tb][r] = -INFINITY;
                    }
            }

            // exp2 (scores pre-scaled into log2 domain) + row-sum (lane owns q)
#pragma unroll
            for (int tb = 0; tb < 4; ++tb)
#pragma unroll
                for (int r = 0; r < 16; r += 4) {
                    float p0 = exp2f(st[tb][r]);
                    float p1 = exp2f(st[tb][r + 1]);
                    float p2 = exp2f(st[tb][r + 2]);
                    float p3 = exp2f(st[tb][r + 3]);
                    st[tb][r] = p0; st[tb][r + 1] = p1;
                    st[tb][r + 2] = p2; st[tb][r + 3] = p3;
                    lsum += (p0 + p1) + (p2 + p3);
                }

            // PV: build P A-frags in registers (cvt_pk + permlane32_swap), no LDS
            __builtin_amdgcn_s_setprio(1);
#pragma unroll
            for (int tb = 0; tb < 4; ++tb)
#pragma unroll
                for (int sl = 0; sl < 2; ++sl) {
                    unsigned x0, y0, x1, y1;
                    asm("v_cvt_pk_bf16_f32 %0, %1, %2" : "=v"(x0)
                        : "v"(st[tb][sl * 8 + 0]), "v"(st[tb][sl * 8 + 1]));
                    asm("v_cvt_pk_bf16_f32 %0, %1, %2" : "=v"(y0)
                        : "v"(st[tb][sl * 8 + 4]), "v"(st[tb][sl * 8 + 5]));
                    asm("v_cvt_pk_bf16_f32 %0, %1, %2" : "=v"(x1)
                        : "v"(st[tb][sl * 8 + 2]), "v"(st[tb][sl * 8 + 3]));
                    asm("v_cvt_pk_bf16_f32 %0, %1, %2" : "=v"(y1)
                        : "v"(st[tb][sl * 8 + 6]), "v"(st[tb][sl * 8 + 7]));
                    // x' = [x_lo, y_lo] -> dword0/1 ; y' = [x_hi, y_hi] -> dword2/3
                    asm("v_permlane32_swap_b32 %0, %1" : "+v"(x0), "+v"(y0));
                    asm("v_permlane32_swap_b32 %0, %1" : "+v"(x1), "+v"(y1));
                    uintx4 pd;
                    pd[0] = x0; pd[1] = x1; pd[2] = y0; pd[3] = y1;
                    short8 pa = __builtin_bit_cast(short8, pd);
                    int s = tb * 2 + sl;
#pragma unroll
                    for (int eb = 0; eb < 2; ++eb) {
                        // B=V frag: col e = eb*32 + lane&31, k = t = s*16 + hi*8 + j
                        short8 v = *(const short8*)(Vt + (eb * 32 + l31) * 128 +
                                                    (((s * 2 + hi) ^ l7) << 3));
                        acc[eb] = __builtin_amdgcn_mfma_f32_32x32x16_bf16(pa, v, acc[eb], 0, 0, 0);
                    }
                }
            __builtin_amdgcn_s_setprio(0);
            __syncthreads();  // protects Kt/Vt restage next iteration
        }

        // each q's full row-sum lives split across lane and lane^32
        float lt = lsum + __shfl_xor(lsum, 32);
        float invl = 1.0f / lt;

        // O layout: row q_local = (r&3)+8*(r>>2)+4*hi, col e = eb*32 + lane&31
#pragma unroll
        for (int r = 0; r < 16; ++r) {
            int q_local = (r & 3) + 8 * (r >> 2) + 4 * hi;
            float iv = __shfl(invl, q_local);  // invl for q=q_local lives at lane q_local
            int row = q0 + w * 32 + q_local;
            short* OC = CC + ((size_t)b * S_ + row) * D_ + h * DH_;
#pragma unroll
            for (int eb = 0; eb < 2; ++eb)
                OC[eb * 32 + l31] = f2bf(acc[eb][r] * iv);
        }
    }
}

extern "C" void kernel_launch(void* const* d_in, const int* in_sizes, int n_in,
                              void* d_out, int out_size, void* d_ws, size_t ws_size,
                              hipStream_t stream) {
    const float* x  = (const float*)d_in[0];
    const float* Wq = (const float*)d_in[1];
    const float* Wk = (const float*)d_in[2];
    const float* Wv = (const float*)d_in[3];
    const float* Wo = (const float*)d_in[4];
    const float* bo = (const float*)d_in[5];
    float* out = (float*)d_out;
    short* ws = (short*)d_ws;

    const size_t WSZ = (size_t)H_ * D_ * DH_;        // 1,048,576
    const size_t QSZ = (size_t)B_ * H_ * S_ * DH_;   // 8,388,608
    short* WqT = ws;
    short* WkT = WqT + WSZ;
    short* WvT = WkT + WSZ;
    short* WoT = WvT + WSZ;
    short* xb  = WoT + (size_t)D_ * D_;
    short* Qb  = xb + (size_t)B_ * S_ * D_;
    short* Kb  = Qb + QSZ;
    short* VTb = Kb + QSZ;
    short* CCb = VTb + QSZ;

    convert_x<<<(B_ * S_ * D_ / 8 + 255) / 256, 256, 0, stream>>>(x, xb, B_ * S_ * D_ / 8);
    prep_weights<<<dim3(16, 16, 4), 256, 0, stream>>>(Wq, Wk, Wv, Wo, WqT, WkT, WvT, WoT);
    qkv_gemm128<<<dim3(64, 8, 3), 256, 0, stream>>>(xb, WqT, WkT, WvT, Qb, Kb, VTb);
    attn_kernel<<<dim3(64, 8), 256, 0, stream>>>(Qb, Kb, VTb, CCb);
    outproj128<<<dim3(64, 8), 256, 0, stream>>>(CCb, WoT, bo, out);
}